// Round 1
// baseline (2277.036 us; speedup 1.0000x reference)
//
#include <hip/hip_runtime.h>
#include <math.h>

#define N_NODES 100000
#define N_EDGES 1600000
#define IN_F    128
#define NH1     8
#define HID     8
#define C1      64   // NH1*HID
#define C2      40   // N_CLASSES

// ---- float atomic-max via monotonic int encoding ----
__device__ __forceinline__ int enc_f(float x) {
    int i = __float_as_int(x);
    return i >= 0 ? i : (i ^ 0x7FFFFFFF);
}
__device__ __forceinline__ float dec_f(int e) {
    return __int_as_float(e >= 0 ? e : (e ^ 0x7FFFFFFF));
}
__device__ __forceinline__ float lrelu(float x) { return x > 0.f ? x : 0.2f * x; }

// ---- K1: H1 = x@W1 ; s1[n,h] = sum_f H1*att_src1 ; d1 likewise ----
__global__ __launch_bounds__(64) void k_gemm1(
    const float* __restrict__ x, const float* __restrict__ W1,
    const float* __restrict__ as1, const float* __restrict__ ad1,
    float* __restrict__ H1, float* __restrict__ s1, float* __restrict__ d1)
{
    __shared__ float xs[IN_F];
    int n = blockIdx.x, t = threadIdx.x;
    ((float2*)xs)[t] = ((const float2*)(x + (size_t)n * IN_F))[t];
    __syncthreads();
    float acc = 0.f;
    #pragma unroll 8
    for (int k = 0; k < IN_F; k++) acc = fmaf(xs[k], W1[k * C1 + t], acc);
    H1[(size_t)n * C1 + t] = acc;
    float ps = acc * as1[t], pd = acc * ad1[t];  // t == h*8+f indexes [8,8] flat
    #pragma unroll
    for (int off = 4; off; off >>= 1) {
        ps += __shfl_xor(ps, off);
        pd += __shfl_xor(pd, off);
    }
    if ((t & 7) == 0) {
        s1[n * NH1 + (t >> 3)] = ps;
        d1[n * NH1 + (t >> 3)] = pd;
    }
}

// ---- K2: per-edge logits (8 heads), atomicMax into m1[dst,h] ----
__global__ __launch_bounds__(256) void k_max1(
    const int* __restrict__ ei, const float* __restrict__ ea,
    const float* __restrict__ s1, const float* __restrict__ d1,
    const float* __restrict__ ae1, int* __restrict__ m1)
{
    int e = blockIdx.x * blockDim.x + threadIdx.x;
    if (e >= N_EDGES) return;
    int s = ei[e], d = ei[N_EDGES + e];
    float w = ea[e];
    float4 sa = ((const float4*)(s1 + s * NH1))[0];
    float4 sb = ((const float4*)(s1 + s * NH1))[1];
    float4 da = ((const float4*)(d1 + d * NH1))[0];
    float4 db = ((const float4*)(d1 + d * NH1))[1];
    float ls[8] = {sa.x + da.x, sa.y + da.y, sa.z + da.z, sa.w + da.w,
                   sb.x + db.x, sb.y + db.y, sb.z + db.z, sb.w + db.w};
    #pragma unroll
    for (int h = 0; h < 8; h++) {
        float l = lrelu(ls[h] + w * ae1[h]);
        atomicMax(&m1[d * NH1 + h], enc_f(l));
    }
}

// ---- K3: denom1[dst,h] += exp(logit - m1) ----
__global__ __launch_bounds__(256) void k_den1(
    const int* __restrict__ ei, const float* __restrict__ ea,
    const float* __restrict__ s1, const float* __restrict__ d1,
    const float* __restrict__ ae1, const int* __restrict__ m1,
    float* __restrict__ den1)
{
    int e = blockIdx.x * blockDim.x + threadIdx.x;
    if (e >= N_EDGES) return;
    int s = ei[e], d = ei[N_EDGES + e];
    float w = ea[e];
    float4 sa = ((const float4*)(s1 + s * NH1))[0];
    float4 sb = ((const float4*)(s1 + s * NH1))[1];
    float4 da = ((const float4*)(d1 + d * NH1))[0];
    float4 db = ((const float4*)(d1 + d * NH1))[1];
    float ls[8] = {sa.x + da.x, sa.y + da.y, sa.z + da.z, sa.w + da.w,
                   sb.x + db.x, sb.y + db.y, sb.z + db.z, sb.w + db.w};
    #pragma unroll
    for (int h = 0; h < 8; h++) {
        float l = lrelu(ls[h] + w * ae1[h]);
        float p = expf(l - dec_f(m1[d * NH1 + h]));
        atomicAdd(&den1[d * NH1 + h], p);
    }
}

// ---- K4: wave-per-edge scatter: out1[dst, h*8+f] += alpha * H1[src, h*8+f] ----
__global__ __launch_bounds__(256) void k_scat1(
    const int* __restrict__ ei, const float* __restrict__ ea,
    const float* __restrict__ s1, const float* __restrict__ d1,
    const float* __restrict__ ae1, const int* __restrict__ m1,
    const float* __restrict__ den1, const float* __restrict__ H1,
    float* __restrict__ out1)
{
    int wid = (blockIdx.x * blockDim.x + threadIdx.x) >> 6;
    int lane = threadIdx.x & 63;
    if (wid >= N_EDGES) return;
    int s = ei[wid], d = ei[N_EDGES + wid];
    float w = ea[wid];
    int h = lane >> 3;
    float l = lrelu(s1[s * NH1 + h] + d1[d * NH1 + h] + w * ae1[h]);
    float m = dec_f(m1[d * NH1 + h]);
    float den = den1[d * NH1 + h];
    float alpha = expf(l - m) / (den + 1e-16f);
    float v = alpha * H1[(size_t)s * C1 + lane];
    atomicAdd(&out1[(size_t)d * C1 + lane], v);
}

// ---- K5: H2 = elu(out1)@W2 ; s2,d2 dot products ----
__global__ __launch_bounds__(64) void k_gemm2(
    const float* __restrict__ out1, const float* __restrict__ W2,
    const float* __restrict__ as2, const float* __restrict__ ad2,
    float* __restrict__ H2, float* __restrict__ s2, float* __restrict__ d2)
{
    __shared__ float rs[C1];
    int n = blockIdx.x, t = threadIdx.x;
    float r = out1[(size_t)n * C1 + t];
    rs[t] = r > 0.f ? r : expf(r) - 1.f;   // elu(alpha=1)
    __syncthreads();
    float ps = 0.f, pd = 0.f;
    if (t < C2) {
        float acc = 0.f;
        #pragma unroll 8
        for (int k = 0; k < C1; k++) acc = fmaf(rs[k], W2[k * C2 + t], acc);
        H2[(size_t)n * C2 + t] = acc;
        ps = acc * as2[t];
        pd = acc * ad2[t];
    }
    #pragma unroll
    for (int off = 32; off; off >>= 1) {
        ps += __shfl_xor(ps, off);
        pd += __shfl_xor(pd, off);
    }
    if (t == 0) { s2[n] = ps; d2[n] = pd; }
}

// ---- K6: layer-2 edge max ----
__global__ __launch_bounds__(256) void k_max2(
    const int* __restrict__ ei, const float* __restrict__ ea,
    const float* __restrict__ s2, const float* __restrict__ d2,
    const float* __restrict__ ae2, int* __restrict__ m2)
{
    int e = blockIdx.x * blockDim.x + threadIdx.x;
    if (e >= N_EDGES) return;
    int s = ei[e], d = ei[N_EDGES + e];
    float l = lrelu(s2[s] + d2[d] + ea[e] * ae2[0]);
    atomicMax(&m2[d], enc_f(l));
}

// ---- K7: layer-2 denom ----
__global__ __launch_bounds__(256) void k_den2(
    const int* __restrict__ ei, const float* __restrict__ ea,
    const float* __restrict__ s2, const float* __restrict__ d2,
    const float* __restrict__ ae2, const int* __restrict__ m2,
    float* __restrict__ den2)
{
    int e = blockIdx.x * blockDim.x + threadIdx.x;
    if (e >= N_EDGES) return;
    int s = ei[e], d = ei[N_EDGES + e];
    float l = lrelu(s2[s] + d2[d] + ea[e] * ae2[0]);
    atomicAdd(&den2[d], expf(l - dec_f(m2[d])));
}

// ---- K7b: per-edge alpha2 ----
__global__ __launch_bounds__(256) void k_alpha2(
    const int* __restrict__ ei, const float* __restrict__ ea,
    const float* __restrict__ s2, const float* __restrict__ d2,
    const float* __restrict__ ae2, const int* __restrict__ m2,
    const float* __restrict__ den2, float* __restrict__ alpha2)
{
    int e = blockIdx.x * blockDim.x + threadIdx.x;
    if (e >= N_EDGES) return;
    int s = ei[e], d = ei[N_EDGES + e];
    float l = lrelu(s2[s] + d2[d] + ea[e] * ae2[0]);
    alpha2[e] = expf(l - dec_f(m2[d])) / (den2[d] + 1e-16f);
}

// ---- K8: layer-2 scatter: out[dst,c] += alpha2[e] * H2[src,c] ----
__global__ __launch_bounds__(256) void k_scat2(
    const int* __restrict__ ei, const float* __restrict__ alpha2,
    const float* __restrict__ H2, float* __restrict__ out)
{
    int gid = blockIdx.x * blockDim.x + threadIdx.x;   // E*C2 = 64M < 2^31
    if (gid >= N_EDGES * C2) return;
    int e = gid / C2, c = gid - e * C2;
    int s = ei[e], d = ei[N_EDGES + e];
    float v = alpha2[e] * H2[(size_t)s * C2 + c];
    atomicAdd(&out[(size_t)d * C2 + c], v);
}

// ---- K9: in-place log_softmax over 40 classes, wave per node ----
__global__ __launch_bounds__(256) void k_lsm(float* __restrict__ out)
{
    int wid = (blockIdx.x * blockDim.x + threadIdx.x) >> 6;
    int lane = threadIdx.x & 63;
    if (wid >= N_NODES) return;
    float v = lane < C2 ? out[(size_t)wid * C2 + lane] : -INFINITY;
    float m = v;
    #pragma unroll
    for (int off = 32; off; off >>= 1) m = fmaxf(m, __shfl_xor(m, off));
    float p = lane < C2 ? expf(v - m) : 0.f;
    #pragma unroll
    for (int off = 32; off; off >>= 1) p += __shfl_xor(p, off);
    float ls = logf(p);
    if (lane < C2) out[(size_t)wid * C2 + lane] = v - m - ls;
}

extern "C" void kernel_launch(void* const* d_in, const int* in_sizes, int n_in,
                              void* d_out, int out_size, void* d_ws, size_t ws_size,
                              hipStream_t stream)
{
    const float* x   = (const float*)d_in[0];
    const int*   ei  = (const int*)  d_in[1];
    const float* ea  = (const float*)d_in[2];
    const float* W1  = (const float*)d_in[3];
    const float* as1 = (const float*)d_in[4];
    const float* ad1 = (const float*)d_in[5];
    const float* ae1 = (const float*)d_in[6];
    const float* W2  = (const float*)d_in[7];
    const float* as2 = (const float*)d_in[8];
    const float* ad2 = (const float*)d_in[9];
    const float* ae2 = (const float*)d_in[10];
    float* out = (float*)d_out;

    // workspace layout (floats); H2 aliases H1 (H1 dead after k_scat1)
    float* ws     = (float*)d_ws;
    float* H1     = ws;                    // 6.40M
    float* H2     = ws;                    // 4.00M (alias, used after H1 dead)
    float* out1   = ws + 6400000;          // 6.40M
    float* s1     = ws + 12800000;         // 0.80M
    float* d1     = ws + 13600000;         // 0.80M
    int*   m1     = (int*)(ws + 14400000); // 0.80M
    float* den1   = ws + 15200000;         // 0.80M
    float* s2     = ws + 16000000;         // 0.10M
    float* d2     = ws + 16100000;         // 0.10M
    int*   m2     = (int*)(ws + 16200000); // 0.10M
    float* den2   = ws + 16300000;         // 0.10M
    float* alpha2 = ws + 16400000;         // 1.60M  -> total 18.0M floats = 72MB

    // init accumulators (0x80 pattern decodes to ~-3.4e38 under enc_f — safe -inf)
    hipMemsetAsync(out1, 0,    6400000 * 4, stream);
    hipMemsetAsync(den1, 0,     800000 * 4, stream);
    hipMemsetAsync(m1,   0x80,  800000 * 4, stream);
    hipMemsetAsync(den2, 0,     100000 * 4, stream);
    hipMemsetAsync(m2,   0x80,  100000 * 4, stream);
    hipMemsetAsync(out,  0,    4000000 * 4, stream);

    k_gemm1 <<<N_NODES, 64, 0, stream>>>(x, W1, as1, ad1, H1, s1, d1);
    k_max1  <<<(N_EDGES + 255) / 256, 256, 0, stream>>>(ei, ea, s1, d1, ae1, m1);
    k_den1  <<<(N_EDGES + 255) / 256, 256, 0, stream>>>(ei, ea, s1, d1, ae1, m1, den1);
    k_scat1 <<<N_EDGES / 4, 256, 0, stream>>>(ei, ea, s1, d1, ae1, m1, den1, H1, out1);
    k_gemm2 <<<N_NODES, 64, 0, stream>>>(out1, W2, as2, ad2, H2, s2, d2);
    k_max2  <<<(N_EDGES + 255) / 256, 256, 0, stream>>>(ei, ea, s2, d2, ae2, m2);
    k_den2  <<<(N_EDGES + 255) / 256, 256, 0, stream>>>(ei, ea, s2, d2, ae2, m2, den2);
    k_alpha2<<<(N_EDGES + 255) / 256, 256, 0, stream>>>(ei, ea, s2, d2, ae2, m2, den2, alpha2);
    k_scat2 <<<(N_EDGES * C2) / 256, 256, 0, stream>>>(ei, alpha2, H2, out);
    k_lsm   <<<(N_NODES * 64) / 256, 256, 0, stream>>>(out);
}

// Round 2
// 955.694 us; speedup vs baseline: 2.3826x; 2.3826x over previous
//
#include <hip/hip_runtime.h>
#include <math.h>

#define N_NODES 100000
#define N_EDGES 1600000
#define IN_F    128
#define NH1     8
#define HID     8
#define C1      64   // NH1*HID
#define C2      40   // N_CLASSES

__device__ __forceinline__ float lrelu(float x) { return x > 0.f ? x : 0.2f * x; }

// ---- K1: H1 = x@W1 ; s1[n,h] = sum_f H1*att_src1 ; d1 likewise ----
__global__ __launch_bounds__(64) void k_gemm1(
    const float* __restrict__ x, const float* __restrict__ W1,
    const float* __restrict__ as1, const float* __restrict__ ad1,
    float* __restrict__ H1, float* __restrict__ s1, float* __restrict__ d1)
{
    __shared__ float xs[IN_F];
    int n = blockIdx.x, t = threadIdx.x;
    ((float2*)xs)[t] = ((const float2*)(x + (size_t)n * IN_F))[t];
    __syncthreads();
    float acc = 0.f;
    #pragma unroll 8
    for (int k = 0; k < IN_F; k++) acc = fmaf(xs[k], W1[k * C1 + t], acc);
    H1[(size_t)n * C1 + t] = acc;
    float ps = acc * as1[t], pd = acc * ad1[t];  // t == h*8+f indexes [8,8] flat
    #pragma unroll
    for (int off = 4; off; off >>= 1) {
        ps += __shfl_xor(ps, off);
        pd += __shfl_xor(pd, off);
    }
    if ((t & 7) == 0) {
        s1[n * NH1 + (t >> 3)] = ps;
        d1[n * NH1 + (t >> 3)] = pd;
    }
}

// ---- CSR build: degree count ----
__global__ __launch_bounds__(256) void k_count(
    const int* __restrict__ ei, int* __restrict__ deg)
{
    int e = blockIdx.x * blockDim.x + threadIdx.x;
    if (e >= N_EDGES) return;
    atomicAdd(&deg[ei[N_EDGES + e]], 1);
}

// ---- CSR build: exclusive scan (single block, 1024 threads, chunked) ----
__global__ __launch_bounds__(1024) void k_scan(
    const int* __restrict__ deg, int* __restrict__ rowptr)
{
    __shared__ int sums[1024];
    const int CH = (N_NODES + 1023) / 1024;  // 98
    int t = threadIdx.x;
    int base = t * CH;
    int s = 0;
    for (int i = 0; i < CH; i++) {
        int idx = base + i;
        if (idx < N_NODES) s += deg[idx];
    }
    sums[t] = s;
    __syncthreads();
    for (int off = 1; off < 1024; off <<= 1) {
        int v = (t >= off) ? sums[t - off] : 0;
        __syncthreads();
        sums[t] += v;
        __syncthreads();
    }
    int run = (t == 0) ? 0 : sums[t - 1];
    for (int i = 0; i < CH; i++) {
        int idx = base + i;
        if (idx <= N_NODES) rowptr[idx] = run;
        if (idx < N_NODES) run += deg[idx];
    }
}

// ---- CSR build: fill permuted src / edge-attr arrays ----
__global__ __launch_bounds__(256) void k_fill(
    const int* __restrict__ ei, const float* __restrict__ ea,
    const int* __restrict__ rowptr, int* __restrict__ cur,
    int* __restrict__ srcs, float* __restrict__ eap)
{
    int e = blockIdx.x * blockDim.x + threadIdx.x;
    if (e >= N_EDGES) return;
    int s = ei[e], d = ei[N_EDGES + e];
    int pos = rowptr[d] + atomicAdd(&cur[d], 1);
    srcs[pos] = s;
    eap[pos] = ea[e];
}

// ---- K_node1: wave per dst node. One pass over in-edges: softmax-weighted
//      aggregation (no max-subtraction: logits bounded small), then fused
//      elu + GEMM2 (via in-wave shfl broadcast) + s2/d2 dot products. ----
__global__ __launch_bounds__(256) void k_node1(
    const int* __restrict__ rowptr, const int* __restrict__ srcs,
    const float* __restrict__ eap,
    const float* __restrict__ s1, const float* __restrict__ d1,
    const float* __restrict__ ae1, const float* __restrict__ H1,
    const float* __restrict__ W2, const float* __restrict__ as2,
    const float* __restrict__ ad2,
    float* __restrict__ H2, float* __restrict__ s2, float* __restrict__ d2)
{
    int w = (blockIdx.x * blockDim.x + threadIdx.x) >> 6;
    int lane = threadIdx.x & 63;
    if (w >= N_NODES) return;
    int h = lane >> 3;
    float d1v = d1[w * NH1 + h];
    float aeh = ae1[h];
    int jb = rowptr[w], je = rowptr[w + 1];
    float den = 0.f, acc = 0.f;
    for (int j = jb; j < je; ++j) {
        int src = srcs[j];
        float wgt = eap[j];
        float l = lrelu(s1[src * NH1 + h] + d1v + wgt * aeh);
        float p = __expf(l);
        den += p;
        acc = fmaf(p, H1[(size_t)src * C1 + lane], acc);
    }
    float o = acc / (den + 1e-16f);
    float r = o > 0.f ? o : __expf(o) - 1.f;   // elu
    // GEMM2 row: h2[c] = sum_k elu_row[k] * W2[k,c], c = lane (<C2)
    int c = lane < C2 ? lane : 0;
    float h2 = 0.f;
    #pragma unroll 8
    for (int k = 0; k < C1; ++k) {
        float rk = __shfl(r, k);
        h2 = fmaf(rk, W2[k * C2 + c], h2);
    }
    float ps = lane < C2 ? h2 * as2[c] : 0.f;
    float pd = lane < C2 ? h2 * ad2[c] : 0.f;
    #pragma unroll
    for (int off = 32; off; off >>= 1) {
        ps += __shfl_xor(ps, off);
        pd += __shfl_xor(pd, off);
    }
    if (lane < C2) H2[(size_t)w * C2 + lane] = h2;
    if (lane == 0) { s2[w] = ps; d2[w] = pd; }
}

// ---- K_node2: wave per dst node, lane = class. Layer-2 aggregation
//      + fused log_softmax, writes final output. ----
__global__ __launch_bounds__(256) void k_node2(
    const int* __restrict__ rowptr, const int* __restrict__ srcs,
    const float* __restrict__ eap,
    const float* __restrict__ s2, const float* __restrict__ d2,
    const float* __restrict__ ae2, const float* __restrict__ H2,
    float* __restrict__ out)
{
    int w = (blockIdx.x * blockDim.x + threadIdx.x) >> 6;
    int lane = threadIdx.x & 63;
    if (w >= N_NODES) return;
    float d2v = d2[w];
    float aev = ae2[0];
    int c = lane < C2 ? lane : 0;
    int jb = rowptr[w], je = rowptr[w + 1];
    float den = 0.f, acc = 0.f;
    for (int j = jb; j < je; ++j) {
        int src = srcs[j];
        float wgt = eap[j];
        float l = lrelu(s2[src] + d2v + wgt * aev);
        float p = __expf(l);
        den += p;
        acc = fmaf(p, H2[(size_t)src * C2 + c], acc);
    }
    float o = acc / (den + 1e-16f);
    // log_softmax over classes (lanes >= C2 are identity elements)
    float v = lane < C2 ? o : -INFINITY;
    float m = v;
    #pragma unroll
    for (int off = 32; off; off >>= 1) m = fmaxf(m, __shfl_xor(m, off));
    float p = lane < C2 ? __expf(v - m) : 0.f;
    #pragma unroll
    for (int off = 32; off; off >>= 1) p += __shfl_xor(p, off);
    float ls = __logf(p);
    if (lane < C2) out[(size_t)w * C2 + lane] = v - m - ls;
}

extern "C" void kernel_launch(void* const* d_in, const int* in_sizes, int n_in,
                              void* d_out, int out_size, void* d_ws, size_t ws_size,
                              hipStream_t stream)
{
    const float* x   = (const float*)d_in[0];
    const int*   ei  = (const int*)  d_in[1];
    const float* ea  = (const float*)d_in[2];
    const float* W1  = (const float*)d_in[3];
    const float* as1 = (const float*)d_in[4];
    const float* ad1 = (const float*)d_in[5];
    const float* ae1 = (const float*)d_in[6];
    const float* W2  = (const float*)d_in[7];
    const float* as2 = (const float*)d_in[8];
    const float* ad2 = (const float*)d_in[9];
    const float* ae2 = (const float*)d_in[10];
    float* out = (float*)d_out;

    // workspace layout (4B units) — total ~62.9 MB
    float* ws     = (float*)d_ws;
    float* H1     = ws;                          // 6,400,000
    float* H2     = ws + 6400000;                // 4,000,000
    float* s1     = ws + 10400000;               //   800,000
    float* d1     = ws + 11200000;               //   800,000
    float* s2     = ws + 12000000;               //   100,000
    float* d2     = ws + 12100000;               //   100,000
    int*   deg    = (int*)(ws + 12200000);       //   100,000
    int*   rowptr = (int*)(ws + 12300000);       //   100,001
    int*   cur    = (int*)(ws + 12400008);       //   100,000
    int*   srcs   = (int*)(ws + 12500008);       // 1,600,000
    float* eap    = ws + 14100008;               // 1,600,000

    hipMemsetAsync(deg, 0, 100000 * 4, stream);
    hipMemsetAsync(cur, 0, 100000 * 4, stream);

    k_gemm1<<<N_NODES, 64, 0, stream>>>(x, W1, as1, ad1, H1, s1, d1);
    k_count<<<(N_EDGES + 255) / 256, 256, 0, stream>>>(ei, deg);
    k_scan <<<1, 1024, 0, stream>>>(deg, rowptr);
    k_fill <<<(N_EDGES + 255) / 256, 256, 0, stream>>>(ei, ea, rowptr, cur, srcs, eap);
    k_node1<<<(N_NODES + 3) / 4, 256, 0, stream>>>(rowptr, srcs, eap, s1, d1, ae1,
                                                   H1, W2, as2, ad2, H2, s2, d2);
    k_node2<<<(N_NODES + 3) / 4, 256, 0, stream>>>(rowptr, srcs, eap, s2, d2, ae2,
                                                   H2, out);
}

// Round 3
// 803.712 us; speedup vs baseline: 2.8331x; 1.1891x over previous
//
#include <hip/hip_runtime.h>
#include <math.h>

#define N_NODES 100000
#define N_EDGES 1600000
#define IN_F    128
#define NH1     8
#define HID     8
#define C1      64   // NH1*HID
#define C2      40   // N_CLASSES

typedef unsigned short ushort_t;
typedef unsigned int uint_t;

__device__ __forceinline__ float lrelu(float x) { return x > 0.f ? x : 0.2f * x; }
__device__ __forceinline__ ushort_t f2bf(float f) {
    uint_t u = __float_as_uint(f);
    u = (u + 0x7FFFu + ((u >> 16) & 1u)) >> 16;   // round-to-nearest-even
    return (ushort_t)u;
}
__device__ __forceinline__ float bf2f(ushort_t s) {
    return __uint_as_float(((uint_t)s) << 16);
}

// ---- K1: H1(bf16) = x@W1 ; s1[n,h], d1[n,h] attention dots. 4 nodes/block ----
__global__ __launch_bounds__(256) void k_gemm1(
    const float* __restrict__ x, const float* __restrict__ W1,
    const float* __restrict__ as1, const float* __restrict__ ad1,
    ushort_t* __restrict__ H1, float* __restrict__ s1, float* __restrict__ d1)
{
    __shared__ float xs[4][IN_F];
    int wv = threadIdx.x >> 6, lane = threadIdx.x & 63;
    int n = blockIdx.x * 4 + wv;
    ((float2*)xs[wv])[lane] = ((const float2*)(x + (size_t)n * IN_F))[lane];
    __syncthreads();
    float acc = 0.f;
    #pragma unroll
    for (int k = 0; k < IN_F; k += 4) {
        float4 xk = *(const float4*)&xs[wv][k];
        acc = fmaf(xk.x, W1[(k + 0) * C1 + lane], acc);
        acc = fmaf(xk.y, W1[(k + 1) * C1 + lane], acc);
        acc = fmaf(xk.z, W1[(k + 2) * C1 + lane], acc);
        acc = fmaf(xk.w, W1[(k + 3) * C1 + lane], acc);
    }
    H1[(size_t)n * C1 + lane] = f2bf(acc);
    float ps = acc * as1[lane], pd = acc * ad1[lane];  // lane == h*8+f
    #pragma unroll
    for (int off = 4; off; off >>= 1) {
        ps += __shfl_xor(ps, off);
        pd += __shfl_xor(pd, off);
    }
    if ((lane & 7) == 0) {
        s1[n * NH1 + (lane >> 3)] = ps;
        d1[n * NH1 + (lane >> 3)] = pd;
    }
}

// ---- CSR build: degree count ----
__global__ __launch_bounds__(256) void k_count(
    const int* __restrict__ ei, int* __restrict__ deg)
{
    int e = blockIdx.x * blockDim.x + threadIdx.x;
    if (e >= N_EDGES) return;
    atomicAdd(&deg[ei[N_EDGES + e]], 1);
}

// ---- CSR build: exclusive scan (single block) ----
__global__ __launch_bounds__(1024) void k_scan(
    const int* __restrict__ deg, int* __restrict__ rowptr)
{
    __shared__ int sums[1024];
    const int CH = (N_NODES + 1023) / 1024;
    int t = threadIdx.x;
    int base = t * CH;
    int s = 0;
    for (int i = 0; i < CH; i++) {
        int idx = base + i;
        if (idx < N_NODES) s += deg[idx];
    }
    sums[t] = s;
    __syncthreads();
    for (int off = 1; off < 1024; off <<= 1) {
        int v = (t >= off) ? sums[t - off] : 0;
        __syncthreads();
        sums[t] += v;
        __syncthreads();
    }
    int run = (t == 0) ? 0 : sums[t - 1];
    for (int i = 0; i < CH; i++) {
        int idx = base + i;
        if (idx <= N_NODES) rowptr[idx] = run;
        if (idx < N_NODES) run += deg[idx];
    }
}

// ---- CSR build: fill packed (src, edge_w) pairs ----
__global__ __launch_bounds__(256) void k_fill(
    const int* __restrict__ ei, const float* __restrict__ ea,
    const int* __restrict__ rowptr, int* __restrict__ cur,
    int2* __restrict__ edges)
{
    int e = blockIdx.x * blockDim.x + threadIdx.x;
    if (e >= N_EDGES) return;
    int s = ei[e], d = ei[N_EDGES + e];
    int pos = rowptr[d] + atomicAdd(&cur[d], 1);
    edges[pos] = make_int2(s, __float_as_int(ea[e]));
}

// ---- K_node1: wave per dst node. Softmax-weighted gather (no max pass:
//      logits bounded small) + fused elu + GEMM2 + s2/d2. ----
__global__ __launch_bounds__(256) void k_node1(
    const int* __restrict__ rowptr, const int2* __restrict__ edges,
    const float* __restrict__ s1, const float* __restrict__ d1,
    const float* __restrict__ ae1, const ushort_t* __restrict__ H1,
    const float* __restrict__ W2, const float* __restrict__ as2,
    const float* __restrict__ ad2,
    ushort_t* __restrict__ H2, float* __restrict__ s2, float* __restrict__ d2)
{
    int w = (blockIdx.x * blockDim.x + threadIdx.x) >> 6;
    int lane = threadIdx.x & 63;
    if (w >= N_NODES) return;
    int h = lane >> 3;
    float d1v = d1[w * NH1 + h];
    float aeh = ae1[h];
    int jb = rowptr[w], je = rowptr[w + 1];
    float den = 0.f, acc = 0.f;
    int j = jb;
    for (; j + 1 < je; j += 2) {
        int2 e0 = edges[j], e1 = edges[j + 1];
        float l0 = lrelu(s1[e0.x * NH1 + h] + d1v + __int_as_float(e0.y) * aeh);
        float l1 = lrelu(s1[e1.x * NH1 + h] + d1v + __int_as_float(e1.y) * aeh);
        float p0 = __expf(l0), p1 = __expf(l1);
        float h0 = bf2f(H1[(size_t)e0.x * C1 + lane]);
        float h1 = bf2f(H1[(size_t)e1.x * C1 + lane]);
        den += p0 + p1;
        acc = fmaf(p0, h0, acc);
        acc = fmaf(p1, h1, acc);
    }
    if (j < je) {
        int2 e0 = edges[j];
        float l0 = lrelu(s1[e0.x * NH1 + h] + d1v + __int_as_float(e0.y) * aeh);
        float p0 = __expf(l0);
        den += p0;
        acc = fmaf(p0, bf2f(H1[(size_t)e0.x * C1 + lane]), acc);
    }
    float o = acc / (den + 1e-16f);
    float r = o > 0.f ? o : __expf(o) - 1.f;   // elu
    int c = lane < C2 ? lane : 0;
    float h2 = 0.f;
    #pragma unroll 8
    for (int k = 0; k < C1; ++k) {
        float rk = __shfl(r, k);
        h2 = fmaf(rk, W2[k * C2 + c], h2);
    }
    float ps = lane < C2 ? h2 * as2[c] : 0.f;
    float pd = lane < C2 ? h2 * ad2[c] : 0.f;
    #pragma unroll
    for (int off = 32; off; off >>= 1) {
        ps += __shfl_xor(ps, off);
        pd += __shfl_xor(pd, off);
    }
    if (lane < C2) H2[(size_t)w * C1 + lane] = f2bf(h2);  // stride 64 (padded)
    if (lane == 0) { s2[w] = ps; d2[w] = pd; }
}

// ---- K_node2: wave per dst node, lane = class. Layer-2 aggregation
//      + fused log_softmax. ----
__global__ __launch_bounds__(256) void k_node2(
    const int* __restrict__ rowptr, const int2* __restrict__ edges,
    const float* __restrict__ s2, const float* __restrict__ d2,
    const float* __restrict__ ae2, const ushort_t* __restrict__ H2,
    float* __restrict__ out)
{
    int w = (blockIdx.x * blockDim.x + threadIdx.x) >> 6;
    int lane = threadIdx.x & 63;
    if (w >= N_NODES) return;
    float d2v = d2[w];
    float aev = ae2[0];
    int c = lane < C2 ? lane : 0;
    int jb = rowptr[w], je = rowptr[w + 1];
    float den = 0.f, acc = 0.f;
    int j = jb;
    for (; j + 1 < je; j += 2) {
        int2 e0 = edges[j], e1 = edges[j + 1];
        float l0 = lrelu(s2[e0.x] + d2v + __int_as_float(e0.y) * aev);
        float l1 = lrelu(s2[e1.x] + d2v + __int_as_float(e1.y) * aev);
        float p0 = __expf(l0), p1 = __expf(l1);
        float h0 = bf2f(H2[(size_t)e0.x * C1 + c]);
        float h1 = bf2f(H2[(size_t)e1.x * C1 + c]);
        den += p0 + p1;
        acc = fmaf(p0, h0, acc);
        acc = fmaf(p1, h1, acc);
    }
    if (j < je) {
        int2 e0 = edges[j];
        float l0 = lrelu(s2[e0.x] + d2v + __int_as_float(e0.y) * aev);
        float p0 = __expf(l0);
        den += p0;
        acc = fmaf(p0, bf2f(H2[(size_t)e0.x * C1 + c]), acc);
    }
    float o = acc / (den + 1e-16f);
    float v = lane < C2 ? o : -INFINITY;
    float m = v;
    #pragma unroll
    for (int off = 32; off; off >>= 1) m = fmaxf(m, __shfl_xor(m, off));
    float p = lane < C2 ? __expf(v - m) : 0.f;
    #pragma unroll
    for (int off = 32; off; off >>= 1) p += __shfl_xor(p, off);
    float ls = __logf(p);
    if (lane < C2) out[(size_t)w * C2 + lane] = v - m - ls;
}

extern "C" void kernel_launch(void* const* d_in, const int* in_sizes, int n_in,
                              void* d_out, int out_size, void* d_ws, size_t ws_size,
                              hipStream_t stream)
{
    const float* x   = (const float*)d_in[0];
    const int*   ei  = (const int*)  d_in[1];
    const float* ea  = (const float*)d_in[2];
    const float* W1  = (const float*)d_in[3];
    const float* as1 = (const float*)d_in[4];
    const float* ad1 = (const float*)d_in[5];
    const float* ae1 = (const float*)d_in[6];
    const float* W2  = (const float*)d_in[7];
    const float* as2 = (const float*)d_in[8];
    const float* ad2 = (const float*)d_in[9];
    const float* ae2 = (const float*)d_in[10];
    float* out = (float*)d_out;

    // workspace layout (4-byte units) — ~47 MB total
    float*    ws     = (float*)d_ws;
    ushort_t* H1     = (ushort_t*)ws;                 // 6.4M bf16 = 3.2M units
    ushort_t* H2     = (ushort_t*)(ws + 3200000);     // 6.4M bf16 (stride-64 padded)
    float*    s1     = ws + 6400000;                  // 800,000
    float*    d1     = ws + 7200000;                  // 800,000
    float*    s2     = ws + 8000000;                  // 100,000
    float*    d2     = ws + 8100000;                  // 100,000
    int*      deg    = (int*)(ws + 8200000);          // 100,000
    int*      rowptr = (int*)(ws + 8300000);          // 100,001
    int*      cur    = (int*)(ws + 8400008);          // 100,000
    int2*     edges  = (int2*)(ws + 8500008);         // 1.6M int2 = 3.2M units

    hipMemsetAsync(deg, 0, 100000 * 4, stream);
    hipMemsetAsync(cur, 0, 100000 * 4, stream);

    k_gemm1<<<N_NODES / 4, 256, 0, stream>>>(x, W1, as1, ad1, H1, s1, d1);
    k_count<<<(N_EDGES + 255) / 256, 256, 0, stream>>>(ei, deg);
    k_scan <<<1, 1024, 0, stream>>>(deg, rowptr);
    k_fill <<<(N_EDGES + 255) / 256, 256, 0, stream>>>(ei, ea, rowptr, cur, edges);
    k_node1<<<(N_NODES + 3) / 4, 256, 0, stream>>>(rowptr, edges, s1, d1, ae1,
                                                   H1, W2, as2, ad2, H2, s2, d2);
    k_node2<<<(N_NODES + 3) / 4, 256, 0, stream>>>(rowptr, edges, s2, d2, ae2,
                                                   H2, out);
}

// Round 4
// 620.172 us; speedup vs baseline: 3.6716x; 1.2960x over previous
//
#include <hip/hip_runtime.h>
#include <math.h>

#define N_NODES 100000
#define N_EDGES 1600000
#define IN_F    128
#define NH1     8
#define HID     8
#define C1      64   // NH1*HID
#define C2      40   // N_CLASSES
#define SCAN_B  256
#define N_SBLK  ((N_NODES + SCAN_B - 1) / SCAN_B)   // 391

typedef unsigned short ushort_t;
typedef unsigned int uint_t;

__device__ __forceinline__ float lrelu(float x) { return x > 0.f ? x : 0.2f * x; }
__device__ __forceinline__ ushort_t f2bf(float f) {
    uint_t u = __float_as_uint(f);
    u = (u + 0x7FFFu + ((u >> 16) & 1u)) >> 16;   // round-to-nearest-even
    return (ushort_t)u;
}
__device__ __forceinline__ float bf2f(ushort_t s) {
    return __uint_as_float(((uint_t)s) << 16);
}

// ---- K1: H1(bf16) = x@W1 ; s1[n,h], d1[n,h] attention dots. 4 nodes/block ----
__global__ __launch_bounds__(256) void k_gemm1(
    const float* __restrict__ x, const float* __restrict__ W1,
    const float* __restrict__ as1, const float* __restrict__ ad1,
    ushort_t* __restrict__ H1, float* __restrict__ s1, float* __restrict__ d1)
{
    __shared__ float xs[4][IN_F];
    int wv = threadIdx.x >> 6, lane = threadIdx.x & 63;
    int n = blockIdx.x * 4 + wv;
    ((float2*)xs[wv])[lane] = ((const float2*)(x + (size_t)n * IN_F))[lane];
    __syncthreads();
    float acc = 0.f;
    #pragma unroll
    for (int k = 0; k < IN_F; k += 4) {
        float4 xk = *(const float4*)&xs[wv][k];
        acc = fmaf(xk.x, W1[(k + 0) * C1 + lane], acc);
        acc = fmaf(xk.y, W1[(k + 1) * C1 + lane], acc);
        acc = fmaf(xk.z, W1[(k + 2) * C1 + lane], acc);
        acc = fmaf(xk.w, W1[(k + 3) * C1 + lane], acc);
    }
    H1[(size_t)n * C1 + lane] = f2bf(acc);
    float ps = acc * as1[lane], pd = acc * ad1[lane];  // lane == h*8+f
    #pragma unroll
    for (int off = 4; off; off >>= 1) {
        ps += __shfl_xor(ps, off);
        pd += __shfl_xor(pd, off);
    }
    if ((lane & 7) == 0) {
        s1[n * NH1 + (lane >> 3)] = ps;
        d1[n * NH1 + (lane >> 3)] = pd;
    }
}

// ---- CSR build: degree count ----
__global__ __launch_bounds__(256) void k_count(
    const int* __restrict__ ei, int* __restrict__ deg)
{
    int e = blockIdx.x * blockDim.x + threadIdx.x;
    if (e >= N_EDGES) return;
    atomicAdd(&deg[ei[N_EDGES + e]], 1);
}

// ---- scan phase 1: per-block (256-wide) reduction of deg -> bsum ----
__global__ __launch_bounds__(SCAN_B) void k_red(
    const int* __restrict__ deg, int* __restrict__ bsum)
{
    int t = threadIdx.x, lane = t & 63, wv = t >> 6;
    int i = blockIdx.x * SCAN_B + t;
    int v = (i < N_NODES) ? deg[i] : 0;
    #pragma unroll
    for (int off = 32; off; off >>= 1) v += __shfl_xor(v, off);
    __shared__ int s[4];
    if (lane == 0) s[wv] = v;
    __syncthreads();
    if (t == 0) bsum[blockIdx.x] = s[0] + s[1] + s[2] + s[3];
}

// ---- scan phase 2: single small block scans the 391 block sums ----
__global__ __launch_bounds__(512) void k_scan_small(
    const int* __restrict__ bsum, int* __restrict__ boff,
    int* __restrict__ rowptr)
{
    __shared__ int s[512];
    int t = threadIdx.x;
    int v = (t < N_SBLK) ? bsum[t] : 0;
    s[t] = v;
    __syncthreads();
    for (int off = 1; off < 512; off <<= 1) {
        int u = (t >= off) ? s[t - off] : 0;
        __syncthreads();
        s[t] += u;
        __syncthreads();
    }
    if (t < N_SBLK) boff[t] = s[t] - v;          // exclusive
    if (t == 511) rowptr[N_NODES] = s[511];      // total == N_EDGES
}

// ---- scan phase 3: in-block exclusive scan + block offset -> rowptr ----
__global__ __launch_bounds__(SCAN_B) void k_apply(
    const int* __restrict__ deg, const int* __restrict__ boff,
    int* __restrict__ rowptr)
{
    int t = threadIdx.x, lane = t & 63, wv = t >> 6;
    int i = blockIdx.x * SCAN_B + t;
    int v = (i < N_NODES) ? deg[i] : 0;
    int inc = v;
    #pragma unroll
    for (int off = 1; off < 64; off <<= 1) {
        int u = __shfl_up(inc, off);
        if (lane >= off) inc += u;
    }
    __shared__ int ws_[4];
    if (lane == 63) ws_[wv] = inc;
    __syncthreads();
    int add = 0;
    for (int k = 0; k < wv; k++) add += ws_[k];
    if (i < N_NODES) rowptr[i] = inc - v + add + boff[blockIdx.x];
}

// ---- CSR build: fill packed (src, edge_w) pairs ----
__global__ __launch_bounds__(256) void k_fill(
    const int* __restrict__ ei, const float* __restrict__ ea,
    const int* __restrict__ rowptr, int* __restrict__ cur,
    int2* __restrict__ edges)
{
    int e = blockIdx.x * blockDim.x + threadIdx.x;
    if (e >= N_EDGES) return;
    int s = ei[e], d = ei[N_EDGES + e];
    int pos = rowptr[d] + atomicAdd(&cur[d], 1);
    edges[pos] = make_int2(s, __float_as_int(ea[e]));
}

// ---- K_node1: wave per dst node. Softmax-weighted gather (no max pass:
//      logits bounded small) + fused elu + GEMM2 + s2/d2. ----
__global__ __launch_bounds__(256) void k_node1(
    const int* __restrict__ rowptr, const int2* __restrict__ edges,
    const float* __restrict__ s1, const float* __restrict__ d1,
    const float* __restrict__ ae1, const ushort_t* __restrict__ H1,
    const float* __restrict__ W2, const float* __restrict__ as2,
    const float* __restrict__ ad2,
    ushort_t* __restrict__ H2, float* __restrict__ s2, float* __restrict__ d2)
{
    int w = (blockIdx.x * blockDim.x + threadIdx.x) >> 6;
    int lane = threadIdx.x & 63;
    if (w >= N_NODES) return;
    int h = lane >> 3;
    float d1v = d1[w * NH1 + h];
    float aeh = ae1[h];
    int jb = rowptr[w], je = rowptr[w + 1];
    float den = 0.f, acc = 0.f;
    int j = jb;
    for (; j + 1 < je; j += 2) {
        int2 e0 = edges[j], e1 = edges[j + 1];
        float l0 = lrelu(s1[e0.x * NH1 + h] + d1v + __int_as_float(e0.y) * aeh);
        float l1 = lrelu(s1[e1.x * NH1 + h] + d1v + __int_as_float(e1.y) * aeh);
        float p0 = __expf(l0), p1 = __expf(l1);
        float h0 = bf2f(H1[(size_t)e0.x * C1 + lane]);
        float h1 = bf2f(H1[(size_t)e1.x * C1 + lane]);
        den += p0 + p1;
        acc = fmaf(p0, h0, acc);
        acc = fmaf(p1, h1, acc);
    }
    if (j < je) {
        int2 e0 = edges[j];
        float l0 = lrelu(s1[e0.x * NH1 + h] + d1v + __int_as_float(e0.y) * aeh);
        float p0 = __expf(l0);
        den += p0;
        acc = fmaf(p0, bf2f(H1[(size_t)e0.x * C1 + lane]), acc);
    }
    float o = acc / (den + 1e-16f);
    float r = o > 0.f ? o : __expf(o) - 1.f;   // elu
    int c = lane < C2 ? lane : 0;
    float h2 = 0.f;
    #pragma unroll 8
    for (int k = 0; k < C1; ++k) {
        float rk = __shfl(r, k);
        h2 = fmaf(rk, W2[k * C2 + c], h2);
    }
    float ps = lane < C2 ? h2 * as2[c] : 0.f;
    float pd = lane < C2 ? h2 * ad2[c] : 0.f;
    #pragma unroll
    for (int off = 32; off; off >>= 1) {
        ps += __shfl_xor(ps, off);
        pd += __shfl_xor(pd, off);
    }
    if (lane < C2) H2[(size_t)w * C1 + lane] = f2bf(h2);  // stride 64 (padded)
    if (lane == 0) { s2[w] = ps; d2[w] = pd; }
}

// ---- K_node2: wave per dst node, lane = class. Layer-2 aggregation
//      + fused log_softmax. ----
__global__ __launch_bounds__(256) void k_node2(
    const int* __restrict__ rowptr, const int2* __restrict__ edges,
    const float* __restrict__ s2, const float* __restrict__ d2,
    const float* __restrict__ ae2, const ushort_t* __restrict__ H2,
    float* __restrict__ out)
{
    int w = (blockIdx.x * blockDim.x + threadIdx.x) >> 6;
    int lane = threadIdx.x & 63;
    if (w >= N_NODES) return;
    float d2v = d2[w];
    float aev = ae2[0];
    int c = lane < C2 ? lane : 0;
    int jb = rowptr[w], je = rowptr[w + 1];
    float den = 0.f, acc = 0.f;
    int j = jb;
    for (; j + 1 < je; j += 2) {
        int2 e0 = edges[j], e1 = edges[j + 1];
        float l0 = lrelu(s2[e0.x] + d2v + __int_as_float(e0.y) * aev);
        float l1 = lrelu(s2[e1.x] + d2v + __int_as_float(e1.y) * aev);
        float p0 = __expf(l0), p1 = __expf(l1);
        float h0 = bf2f(H2[(size_t)e0.x * C1 + c]);
        float h1 = bf2f(H2[(size_t)e1.x * C1 + c]);
        den += p0 + p1;
        acc = fmaf(p0, h0, acc);
        acc = fmaf(p1, h1, acc);
    }
    if (j < je) {
        int2 e0 = edges[j];
        float l0 = lrelu(s2[e0.x] + d2v + __int_as_float(e0.y) * aev);
        float p0 = __expf(l0);
        den += p0;
        acc = fmaf(p0, bf2f(H2[(size_t)e0.x * C1 + c]), acc);
    }
    float o = acc / (den + 1e-16f);
    float v = lane < C2 ? o : -INFINITY;
    float m = v;
    #pragma unroll
    for (int off = 32; off; off >>= 1) m = fmaxf(m, __shfl_xor(m, off));
    float p = lane < C2 ? __expf(v - m) : 0.f;
    #pragma unroll
    for (int off = 32; off; off >>= 1) p += __shfl_xor(p, off);
    float ls = __logf(p);
    if (lane < C2) out[(size_t)w * C2 + lane] = v - m - ls;
}

extern "C" void kernel_launch(void* const* d_in, const int* in_sizes, int n_in,
                              void* d_out, int out_size, void* d_ws, size_t ws_size,
                              hipStream_t stream)
{
    const float* x   = (const float*)d_in[0];
    const int*   ei  = (const int*)  d_in[1];
    const float* ea  = (const float*)d_in[2];
    const float* W1  = (const float*)d_in[3];
    const float* as1 = (const float*)d_in[4];
    const float* ad1 = (const float*)d_in[5];
    const float* ae1 = (const float*)d_in[6];
    const float* W2  = (const float*)d_in[7];
    const float* as2 = (const float*)d_in[8];
    const float* ad2 = (const float*)d_in[9];
    const float* ae2 = (const float*)d_in[10];
    float* out = (float*)d_out;

    // workspace layout (4-byte units) — ~47 MB total
    float*    ws     = (float*)d_ws;
    ushort_t* H1     = (ushort_t*)ws;                 // 6.4M bf16 = 3.2M units
    ushort_t* H2     = (ushort_t*)(ws + 3200000);     // 6.4M bf16 (stride-64 padded)
    float*    s1     = ws + 6400000;                  // 800,000
    float*    d1     = ws + 7200000;                  // 800,000
    float*    s2     = ws + 8000000;                  // 100,000
    float*    d2     = ws + 8100000;                  // 100,000
    int*      deg    = (int*)(ws + 8200000);          // 100,000
    int*      rowptr = (int*)(ws + 8300000);          // 100,001
    int*      cur    = (int*)(ws + 8400008);          // 100,000
    int2*     edges  = (int2*)(ws + 8500008);         // 1.6M int2 = 3.2M units
    int*      bsum   = (int*)(ws + 11700008);         // 391
    int*      boff   = (int*)(ws + 11700400);         // 391

    hipMemsetAsync(deg, 0, 100000 * 4, stream);
    hipMemsetAsync(cur, 0, 100000 * 4, stream);

    k_gemm1     <<<N_NODES / 4, 256, 0, stream>>>(x, W1, as1, ad1, H1, s1, d1);
    k_count     <<<(N_EDGES + 255) / 256, 256, 0, stream>>>(ei, deg);
    k_red       <<<N_SBLK, SCAN_B, 0, stream>>>(deg, bsum);
    k_scan_small<<<1, 512, 0, stream>>>(bsum, boff, rowptr);
    k_apply     <<<N_SBLK, SCAN_B, 0, stream>>>(deg, boff, rowptr);
    k_fill      <<<(N_EDGES + 255) / 256, 256, 0, stream>>>(ei, ea, rowptr, cur, edges);
    k_node1     <<<(N_NODES + 3) / 4, 256, 0, stream>>>(rowptr, edges, s1, d1, ae1,
                                                        H1, W2, as2, ad2, H2, s2, d2);
    k_node2     <<<(N_NODES + 3) / 4, 256, 0, stream>>>(rowptr, edges, s2, d2, ae2,
                                                        H2, out);
}